// Round 1
// baseline (8846.822 us; speedup 1.0000x reference)
//
#include <hip/hip_runtime.h>
#include <cstdint>
#include <cstddef>

// LSTM autoregressive decoder, BATCH=32, T=256, VOCAB=8192, HIDDEN=1024.
// Sequential per-step pipeline: K1 (cell) -> K2 (h@Wp, h@Wh partials) -> K3
// (logits + gumbel argmax partials). jax threefry (partitionable variant)
// reproduced bit-exactly for jax.random.categorical.

namespace {

constexpr int BB = 32;       // batch
constexpr int TT = 256;      // time steps
constexpr int VV = 8192;     // vocab
constexpr int HH = 1024;     // hidden
constexpr int ZC = 4096;     // 4*H
constexpr int NCOL = VV + ZC;   // 12288 columns (logits | z)
constexpr int SPL = 4;       // u-split for K2 (1024/256)
constexpr int K0S = 8;       // u-split for K0 (9216/1152)

__host__ __device__ inline uint32_t rotl(uint32_t v, int r) {
  return (v << r) | (v >> (32 - r));
}

// Exact jax threefry2x32 (20 rounds).
__host__ __device__ inline void tf2x32(uint32_t k0, uint32_t k1,
                                       uint32_t x0, uint32_t x1,
                                       uint32_t &o0, uint32_t &o1) {
  const uint32_t ks2 = k0 ^ k1 ^ 0x1BD11BDAu;
  x0 += k0; x1 += k1;
#define R4A { x0+=x1; x1=rotl(x1,13); x1^=x0; x0+=x1; x1=rotl(x1,15); x1^=x0; \
              x0+=x1; x1=rotl(x1,26); x1^=x0; x0+=x1; x1=rotl(x1, 6); x1^=x0; }
#define R4B { x0+=x1; x1=rotl(x1,17); x1^=x0; x0+=x1; x1=rotl(x1,29); x1^=x0; \
              x0+=x1; x1=rotl(x1,16); x1^=x0; x0+=x1; x1=rotl(x1,24); x1^=x0; }
  R4A; x0 += k1;  x1 += ks2 + 1u;
  R4B; x0 += ks2; x1 += k0 + 2u;
  R4A; x0 += k0;  x1 += k1 + 3u;
  R4B; x0 += k1;  x1 += ks2 + 4u;
  R4A; x0 += ks2; x1 += k0 + 5u;
#undef R4A
#undef R4B
  o0 = x0; o1 = x1;
}

__device__ inline float sigf(float x) { return 1.0f / (1.0f + expf(-x)); }

// ---------------------------------------------------------------------------
// K0: z0 partials = x0 @ Wi + h0 @ Wh  (K = VOCAB + HIDDEN = 9216, split x8)
// grid: (ZC/64) * K0S blocks, 256 threads.
__global__ __launch_bounds__(256) void k0_partial(
    const float* __restrict__ inputs,   // [B][T][V], use t=0
    const float* __restrict__ h0,       // [B][H]
    const float* __restrict__ Wi,       // [V][ZC]
    const float* __restrict__ Wh,       // [H][ZC]
    float* __restrict__ zpart0)         // [K0S][B][ZC]
{
  const int cb = blockIdx.x % (ZC / 64);
  const int s  = blockIdx.x / (ZC / 64);
  const int c  = threadIdx.x & 63;
  const int w  = threadIdx.x >> 6;
  const int col = cb * 64 + c;
  const int u0 = s * 1152 + w * 288;

  float acc[BB];
#pragma unroll
  for (int b = 0; b < BB; ++b) acc[b] = 0.0f;

  for (int ui = 0; ui < 288; ++ui) {
    const int u = u0 + ui;
    const float wv = (u < VV) ? Wi[(size_t)u * ZC + col]
                              : Wh[(size_t)(u - VV) * ZC + col];
#pragma unroll
    for (int b = 0; b < BB; ++b) {
      const float a = (u < VV) ? inputs[(size_t)b * TT * VV + u]
                               : h0[b * HH + (u - VV)];
      acc[b] = fmaf(a, wv, acc[b]);
    }
  }

  __shared__ float red[4][BB][64];   // 32 KiB
#pragma unroll
  for (int b = 0; b < BB; ++b) red[w][b][c] = acc[b];
  __syncthreads();
  for (int i = threadIdx.x; i < BB * 64; i += 256) {
    const int b = i >> 6, cc = i & 63;
    const float s4 = red[0][b][cc] + red[1][b][cc] + red[2][b][cc] + red[3][b][cc];
    zpart0[((size_t)s * BB + b) * ZC + cb * 64 + cc] = s4;
  }
}

// K0b: zfull0[b][j] = bh[j] + sum_s zpart0[s][b][j]
__global__ __launch_bounds__(256) void k0_reduce(
    const float* __restrict__ zpart0, const float* __restrict__ bh,
    float* __restrict__ zfull0)
{
  const int idx = blockIdx.x * 256 + threadIdx.x;  // B*ZC = 131072
  const int b = idx / ZC, j = idx % ZC;
  float s = bh[j];
#pragma unroll
  for (int k = 0; k < K0S; ++k) s += zpart0[((size_t)k * BB + b) * ZC + j];
  zfull0[idx] = s;
}

// ---------------------------------------------------------------------------
// K1: finalize tok(t-1) from argmax partials, write preds one-hot (t-1),
//     assemble z_t (partials + bh + Wi[tok]) and run LSTM cell -> c,h.
// grid: B blocks, 256 threads.
__global__ __launch_bounds__(256) void k1_cell(
    const float* __restrict__ part,     // [SPL][B][NCOL]
    const float* __restrict__ zfull0,   // [B][ZC] (t==0 only)
    const float* __restrict__ bh,       // [ZC]
    const float* __restrict__ Wi,       // [V][ZC]
    const float* __restrict__ c0,       // [B][H]
    const float* __restrict__ argval,   // [B][32]
    const int*   __restrict__ argidx,   // [B][32]
    float* __restrict__ cbuf, float* __restrict__ hbuf,   // [B][H]
    float* __restrict__ preds_out,      // [B][T][V]
    int t)
{
  const int b = blockIdx.x;
  __shared__ int tok_sh;
  if (t > 0) {
    if (threadIdx.x < 64) {
      const int lane = threadIdx.x;
      float v = -3.4e38f; int idx = 0x7fffffff;
      if (lane < 32) { v = argval[b * 32 + lane]; idx = argidx[b * 32 + lane]; }
#pragma unroll
      for (int off = 16; off; off >>= 1) {
        const float vo = __shfl_down(v, off);
        const int   io = __shfl_down(idx, off);
        if (vo > v || (vo == v && io < idx)) { v = vo; idx = io; }
      }
      if (lane == 0) tok_sh = idx;
    }
    __syncthreads();
  }
  const int tok = (t > 0) ? tok_sh : 0;
  if (t > 0 && threadIdx.x == 0) {
    preds_out[((size_t)b * TT + (t - 1)) * VV + tok] = 1.0f;
  }

  for (int u = threadIdx.x; u < HH; u += 256) {
    float zi, zf, zg, zo;
    if (t == 0) {
      const float* z0 = zfull0 + (size_t)b * ZC;
      zi = z0[u]; zf = z0[HH + u]; zg = z0[2 * HH + u]; zo = z0[3 * HH + u];
    } else {
      zi = bh[u]; zf = bh[HH + u]; zg = bh[2 * HH + u]; zo = bh[3 * HH + u];
#pragma unroll
      for (int s = 0; s < SPL; ++s) {
        const float* p = part + ((size_t)s * BB + b) * NCOL + VV;
        zi += p[u]; zf += p[HH + u]; zg += p[2 * HH + u]; zo += p[3 * HH + u];
      }
      const float* wrow = Wi + (size_t)tok * ZC;
      zi += wrow[u]; zf += wrow[HH + u]; zg += wrow[2 * HH + u]; zo += wrow[3 * HH + u];
    }
    const float cprev = (t == 0) ? c0[b * HH + u] : cbuf[b * HH + u];
    const float cc = sigf(zf) * cprev + sigf(zi) * tanhf(zg);
    const float hh = sigf(zo) * tanhf(cc);
    cbuf[b * HH + u] = cc;
    hbuf[b * HH + u] = hh;
  }
}

// ---------------------------------------------------------------------------
// K2: part[s][b][col] partial dot-products for [h@Wp | h@Wh].
// grid: (NCOL/64) * SPL blocks, 256 threads (4 waves, each 64 u's).
__global__ __launch_bounds__(256) void k2_mm(
    const float* __restrict__ hbuf,     // [B][H]
    const float* __restrict__ Wp,       // [H][V]
    const float* __restrict__ Wh,       // [H][ZC]
    float* __restrict__ part)           // [SPL][B][NCOL]
{
  const int cb = blockIdx.x % (NCOL / 64);
  const int s  = blockIdx.x / (NCOL / 64);
  const int c  = threadIdx.x & 63;
  const int w  = threadIdx.x >> 6;
  const int col = cb * 64 + c;

  const float* W; int ldw, wcol;
  if (col < VV) { W = Wp; ldw = VV; wcol = col; }
  else          { W = Wh; ldw = ZC; wcol = col - VV; }

  __shared__ float hs[BB][256];   // 32 KiB, reused as reduce buffer
  for (int i = threadIdx.x; i < BB * 256; i += 256) {
    const int b = i >> 8, uu = i & 255;
    hs[b][uu] = hbuf[b * HH + s * 256 + uu];
  }
  __syncthreads();

  float acc[BB];
#pragma unroll
  for (int b = 0; b < BB; ++b) acc[b] = 0.0f;

  const int ubase = w * 64;
  const float* wp = W + (size_t)(s * 256 + w * 64) * ldw + wcol;
  for (int uc = 0; uc < 8; ++uc) {
    float wv[8];
#pragma unroll
    for (int k = 0; k < 8; ++k) wv[k] = wp[(size_t)(uc * 8 + k) * ldw];
#pragma unroll
    for (int b = 0; b < BB; ++b) {
      const float4 h4a = *(const float4*)&hs[b][ubase + uc * 8];
      const float4 h4b = *(const float4*)&hs[b][ubase + uc * 8 + 4];
      acc[b] = fmaf(h4a.x, wv[0], acc[b]);
      acc[b] = fmaf(h4a.y, wv[1], acc[b]);
      acc[b] = fmaf(h4a.z, wv[2], acc[b]);
      acc[b] = fmaf(h4a.w, wv[3], acc[b]);
      acc[b] = fmaf(h4b.x, wv[4], acc[b]);
      acc[b] = fmaf(h4b.y, wv[5], acc[b]);
      acc[b] = fmaf(h4b.z, wv[6], acc[b]);
      acc[b] = fmaf(h4b.w, wv[7], acc[b]);
    }
  }

  __syncthreads();
  float* red = &hs[0][0];   // [4][B][64] floats = 8192 = same size
#pragma unroll
  for (int b = 0; b < BB; ++b) red[(w * BB + b) * 64 + c] = acc[b];
  __syncthreads();
  for (int i = threadIdx.x; i < BB * 64; i += 256) {
    const int b = i >> 6, cc = i & 63;
    const float s4 = red[(0 * BB + b) * 64 + cc] + red[(1 * BB + b) * 64 + cc] +
                     red[(2 * BB + b) * 64 + cc] + red[(3 * BB + b) * 64 + cc];
    part[((size_t)s * BB + b) * NCOL + cb * 64 + cc] = s4;
  }
}

// ---------------------------------------------------------------------------
// K3: logits = sum_s part + bp -> write out; gumbel via threefry
// (partitionable: bits = o0^o1 of tf(key, 0, flat_idx)); block argmax partial.
// grid: B * (V/256) = 1024 blocks, 256 threads.
__global__ __launch_bounds__(256) void k3_logits(
    const float* __restrict__ part,     // [SPL][B][NCOL]
    const float* __restrict__ bp,       // [V]
    float* __restrict__ logits_out,     // [B][T][V]
    float* __restrict__ preds_out,      // [B][T][V]
    float* __restrict__ argval, int* __restrict__ argidx,   // [B][32]
    uint32_t ck0, uint32_t ck1, int t)
{
  const int b  = blockIdx.x >> 5;
  const int ch = blockIdx.x & 31;
  const int v  = ch * 256 + threadIdx.x;

  float lg = bp[v];
#pragma unroll
  for (int s = 0; s < SPL; ++s) lg += part[((size_t)s * BB + b) * NCOL + v];
  logits_out[((size_t)b * TT + t) * VV + v] = lg;
  preds_out [((size_t)b * TT + t) * VV + v] = 0.0f;

  // gumbel: jax partitionable random_bits, 32-bit -> o0 ^ o1
  const uint32_t j = (uint32_t)(b * VV + v);
  uint32_t r0, r1;
  tf2x32(ck0, ck1, 0u, j, r0, r1);
  const uint32_t bits = r0 ^ r1;
  const float u0 = __uint_as_float((bits >> 9) | 0x3f800000u) - 1.0f;
  const float uu = (u0 == 0.0f) ? 1.17549435e-38f : u0;
  const float g = -logf(-logf(uu));
  const float val = lg + g;

  __shared__ float sval[256];
  __shared__ int   sidx[256];
  sval[threadIdx.x] = val;
  sidx[threadIdx.x] = v;
  __syncthreads();
#pragma unroll
  for (int off = 128; off; off >>= 1) {
    if (threadIdx.x < off) {
      const float vo = sval[threadIdx.x + off];
      const int   io = sidx[threadIdx.x + off];
      if (vo > sval[threadIdx.x] ||
          (vo == sval[threadIdx.x] && io < sidx[threadIdx.x])) {
        sval[threadIdx.x] = vo; sidx[threadIdx.x] = io;
      }
    }
    __syncthreads();
  }
  if (threadIdx.x == 0) {
    argval[b * 32 + ch] = sval[0];
    argidx[b * 32 + ch] = sidx[0];
  }
}

// Final preds row (t = T-1).
__global__ __launch_bounds__(64) void kfinal(
    const float* __restrict__ argval, const int* __restrict__ argidx,
    float* __restrict__ preds_out)
{
  const int b = blockIdx.x, lane = threadIdx.x;
  float v = -3.4e38f; int idx = 0x7fffffff;
  if (lane < 32) { v = argval[b * 32 + lane]; idx = argidx[b * 32 + lane]; }
#pragma unroll
  for (int off = 16; off; off >>= 1) {
    const float vo = __shfl_down(v, off);
    const int   io = __shfl_down(idx, off);
    if (vo > v || (vo == v && io < idx)) { v = vo; idx = io; }
  }
  if (lane == 0) preds_out[((size_t)b * TT + (TT - 1)) * VV + idx] = 1.0f;
}

}  // namespace

extern "C" void kernel_launch(void* const* d_in, const int* in_sizes, int n_in,
                              void* d_out, int out_size, void* d_ws, size_t ws_size,
                              hipStream_t stream) {
  const float* inputs = (const float*)d_in[0];
  const float* Wi     = (const float*)d_in[1];
  const float* Wh     = (const float*)d_in[2];
  const float* bh     = (const float*)d_in[3];
  const float* Wp     = (const float*)d_in[4];
  const float* bp     = (const float*)d_in[5];
  const float* c0     = (const float*)d_in[6];
  const float* h0     = (const float*)d_in[7];

  float* out_logits = (float*)d_out;
  float* out_preds  = out_logits + (size_t)BB * TT * VV;

  // Workspace layout (part overlaps zpart0: disjoint lifetimes).
  uint8_t* ws = (uint8_t*)d_ws;
  size_t off = 0;
  float* part   = (float*)(ws + off);                 // [SPL][B][NCOL]
  float* zpart0 = (float*)(ws + off);                 // [K0S][B][ZC] (overlap)
  off += (size_t)SPL * BB * NCOL * sizeof(float);     // 6.29 MB (>= 4 MB)
  float* zfull0 = (float*)(ws + off); off += (size_t)BB * ZC * sizeof(float);
  float* cbuf   = (float*)(ws + off); off += (size_t)BB * HH * sizeof(float);
  float* hbuf   = (float*)(ws + off); off += (size_t)BB * HH * sizeof(float);
  float* argval = (float*)(ws + off); off += (size_t)BB * 32 * sizeof(float);
  int*   argidx = (int*)  (ws + off); off += (size_t)BB * 32 * sizeof(int);

  // Host-side threefry key chain from jax.random.key(42) = (0, 42).
  // Fold-like split: rng' = tf(rng,0,0); cat = tf(rng,0,1).
  uint32_t k0 = 0u, k1 = 42u;
  uint32_t ck[TT][2];
  for (int t = 0; t < TT; ++t) {
    uint32_t a, b2; tf2x32(k0, k1, 0u, 1u, a, b2);
    ck[t][0] = a; ck[t][1] = b2;
    uint32_t n0, n1; tf2x32(k0, k1, 0u, 0u, n0, n1);
    k0 = n0; k1 = n1;
  }

  k0_partial<<<(ZC / 64) * K0S, 256, 0, stream>>>(inputs, h0, Wi, Wh, zpart0);
  k0_reduce<<<BB * ZC / 256, 256, 0, stream>>>(zpart0, bh, zfull0);

  for (int t = 0; t < TT; ++t) {
    k1_cell<<<BB, 256, 0, stream>>>(part, zfull0, bh, Wi, c0, argval, argidx,
                                    cbuf, hbuf, out_preds, t);
    k2_mm<<<(NCOL / 64) * SPL, 256, 0, stream>>>(hbuf, Wp, Wh, part);
    k3_logits<<<BB * (VV / 256), 256, 0, stream>>>(part, bp, out_logits, out_preds,
                                                   argval, argidx, ck[t][0], ck[t][1], t);
  }
  kfinal<<<BB, 64, 0, stream>>>(argval, argidx, out_preds);
}